// Round 1
// baseline (260.293 us; speedup 1.0000x reference)
//
#include <hip/hip_runtime.h>

typedef __bf16 bf16x8 __attribute__((ext_vector_type(8)));
typedef float f32x4 __attribute__((ext_vector_type(4)));

#define DI __device__ __forceinline__

DI unsigned short f2bf(float f) {
  unsigned int u = __float_as_uint(f);
  u += 0x7FFFu + ((u >> 16) & 1u);
  return (unsigned short)(u >> 16);
}

DI bf16x8 ld16(const void* p) {
  union { uint4 u; bf16x8 b; } c;
  c.u = *reinterpret_cast<const uint4*>(p);
  return c.b;
}

DI f32x4 mfma16(bf16x8 a, bf16x8 b, f32x4 c) {
  return __builtin_amdgcn_mfma_f32_16x16x32_bf16(a, b, c, 0, 0, 0);
}

// global -> LDS direct copy, 16B per lane. LDS dest must be wave-uniform base
// (lane*16 appended by HW); global source is per-lane (pre-swizzled).
DI void gload_lds16(const void* g, void* l) {
  __builtin_amdgcn_global_load_lds(
      (const __attribute__((address_space(1))) unsigned int*)g,
      (__attribute__((address_space(3))) unsigned int*)l, 16, 0, 0);
}

// ---------------- fp32 -> bf16 convert ----------------
__global__ void cvt_bf16(const float* __restrict__ src,
                         unsigned short* __restrict__ dst, int n4) {
  int i = blockIdx.x * blockDim.x + threadIdx.x;
  if (i >= n4) return;
  float4 v = reinterpret_cast<const float4*>(src)[i];
  ushort4 o;
  o.x = f2bf(v.x); o.y = f2bf(v.y); o.z = f2bf(v.z); o.w = f2bf(v.w);
  reinterpret_cast<ushort4*>(dst)[i] = o;
}

// ---------------- GEMM: C[M,N] = A[M,K] * W[N,K]^T + bias ----------------
// 128x128 tile, BK=64, 4 waves (2x2), 16x16x32 bf16 MFMA.
// LDS tiles are linear [128][64] bf16 with XOR bank-swizzle applied on the
// *global source address* during global_load_lds staging and again on the
// ds_read side (involution).
// MODE 0: out = fp32 row-major [M][N] (+bias)
// MODE 1: qkv scatter -> Q (scaled 1/8), K head-major [bh][t][d]; V transposed [bh][d][t]
template <int N, int MODE>
__global__ __launch_bounds__(256)
void gemm_bt(const unsigned short* __restrict__ A,
             const unsigned short* __restrict__ W,
             const float* __restrict__ bias,
             float* __restrict__ out,
             unsigned short* __restrict__ qo,
             unsigned short* __restrict__ ko,
             unsigned short* __restrict__ vo) {
  constexpr int K = 1024;
  __shared__ __align__(16) char smem[32768];
  char* Asm = smem;
  char* Bsm = smem + 16384;
  const int tid = threadIdx.x;
  const int ln = tid & 63;
  const int w  = tid >> 6;
  const int wm = w >> 1, wn = w & 1;
  const int g = ln >> 4, q = ln & 15;
  const int m0 = blockIdx.x * 128;
  const int n0 = blockIdx.y * 128;

  f32x4 acc[4][4] = {};

  for (int kt = 0; kt < K / 64; ++kt) {
    if (kt) __syncthreads();
#pragma unroll
    for (int i = 0; i < 4; ++i) {
      const int chunk = i * 4 + w;
      const int o = chunk * 1024 + ln * 16;
      const int row = o >> 7;
      const int colb = (o & 127) ^ ((row & 7) << 4);
      gload_lds16((const char*)A + ((size_t)(m0 + row) * K + kt * 64) * 2 + colb,
                  Asm + chunk * 1024);
      gload_lds16((const char*)W + ((size_t)(n0 + row) * K + kt * 64) * 2 + colb,
                  Bsm + chunk * 1024);
    }
    asm volatile("s_waitcnt vmcnt(0)" ::: "memory");
    __syncthreads();
#pragma unroll
    for (int ks = 0; ks < 2; ++ks) {
      bf16x8 av[4], bv[4];
#pragma unroll
      for (int mf = 0; mf < 4; ++mf) {
        const int row = wm * 64 + mf * 16 + q;
        const int off = (row * 128 + ks * 64 + g * 16) ^ ((row & 7) << 4);
        av[mf] = ld16(Asm + off);
      }
#pragma unroll
      for (int nf = 0; nf < 4; ++nf) {
        const int row = wn * 64 + nf * 16 + q;
        const int off = (row * 128 + ks * 64 + g * 16) ^ ((row & 7) << 4);
        bv[nf] = ld16(Bsm + off);
      }
#pragma unroll
      for (int mf = 0; mf < 4; ++mf)
#pragma unroll
        for (int nf = 0; nf < 4; ++nf)
          acc[mf][nf] = mfma16(av[mf], bv[nf], acc[mf][nf]);
    }
  }

#pragma unroll
  for (int nf = 0; nf < 4; ++nf) {
    const int col = n0 + wn * 64 + nf * 16 + q;
    const float bv = bias[col];
#pragma unroll
    for (int mf = 0; mf < 4; ++mf) {
      const int rbase = m0 + wm * 64 + mf * 16 + g * 4;
#pragma unroll
      for (int r = 0; r < 4; ++r) {
        const int row = rbase + r;
        const float v = acc[mf][nf][r] + bv;
        if constexpr (MODE == 0) {
          out[(size_t)row * N + col] = v;
        } else {
          const int b = row >> 11, t = row & 2047;
          if (col < 1024) {
            const int h = col >> 6, d = col & 63;
            qo[((((size_t)b * 16 + h) << 11) + t) * 64 + d] = f2bf(v * 0.125f);
          } else if (col < 2048) {
            const int c = col - 1024;
            const int h = c >> 6, d = c & 63;
            ko[((((size_t)b * 16 + h) << 11) + t) * 64 + d] = f2bf(v);
          } else {
            const int c = col - 2048;
            const int h = c >> 6, d = c & 63;
            vo[((((size_t)b * 16 + h) << 6) + d) * 2048 + t] = f2bf(v);
          }
        }
      }
    }
  }
}

// ---------------- flash attention (causal), swapped-operand form ----------------
// grid: (T/128, B*H). 4 waves, wave w owns q rows [q0+32w, q0+32w+32).
// S^T = mfma(K_frag, Q_frag): lane holds q-col = l&15, kv rows 4*(l>>4)+r.
// Softmax reduce over kv = in-lane (mf,r) + shfl_xor 16,32.
// P^T staged per-wave in swizzled LDS; Y^T = mfma(Vt_frag, P_frag).
__global__ __launch_bounds__(256)
void attn_fwd(const unsigned short* __restrict__ Qb,
              const unsigned short* __restrict__ Kb,
              const unsigned short* __restrict__ Vtb,
              unsigned short* __restrict__ Yb) {
  __shared__ __align__(16) char smem[32768];
  char* Ksm = smem;          // [64 kv][64 d] bf16, swizzled
  char* Vsm = smem + 8192;   // [64 d][64 kv] bf16, swizzled
  char* Psm = smem + 16384;  // [128 q][64 kv] bf16, swizzled, per-wave 32-row slice
  const int tid = threadIdx.x;
  const int ln = tid & 63;
  const int w = tid >> 6;
  const int g = ln >> 4, q = ln & 15;
  const int qt = blockIdx.x, bh = blockIdx.y;
  const int q0 = qt * 128;
  const int qw = q0 + w * 32;
  const size_t base = (size_t)bh * 2048 * 64;  // elements

  bf16x8 qf[2][2];
#pragma unroll
  for (int nf = 0; nf < 2; ++nf)
#pragma unroll
    for (int kf = 0; kf < 2; ++kf)
      qf[nf][kf] = ld16(Qb + base + (size_t)(qw + nf * 16 + q) * 64 + kf * 32 + g * 8);

  float m_run[2] = {-INFINITY, -INFINITY};
  float l_run[2] = {0.f, 0.f};
  f32x4 yt[4][2] = {};

  const int nkv = (q0 >> 6) + 2;
  for (int j = 0; j < nkv; ++j) {
    const int kv0 = j << 6;
    if (j) __syncthreads();
    {
      const char* Kg = (const char*)(Kb + base + (size_t)kv0 * 64);
      const char* Vg = (const char*)(Vtb + base) + kv0 * 2;
#pragma unroll
      for (int i = 0; i < 2; ++i) {
        const int chunk = i * 4 + w;
        const int o = chunk * 1024 + ln * 16;
        const int row = o >> 7;
        const int colb = (o & 127) ^ ((row & 7) << 4);
        gload_lds16(Kg + row * 128 + colb, Ksm + chunk * 1024);
        gload_lds16(Vg + (size_t)row * 4096 + colb, Vsm + chunk * 1024);
      }
    }
    asm volatile("s_waitcnt vmcnt(0)" ::: "memory");
    __syncthreads();

    const bool active = (kv0 <= qw + 31);
    if (active) {
      f32x4 st[4][2] = {};
#pragma unroll
      for (int mf = 0; mf < 4; ++mf) {
        const int row = mf * 16 + q;
        const int swz = (row & 7) << 4;
        const bf16x8 a0 = ld16(Ksm + ((row * 128 + g * 16) ^ swz));
        const bf16x8 a1 = ld16(Ksm + ((row * 128 + 64 + g * 16) ^ swz));
#pragma unroll
        for (int nf = 0; nf < 2; ++nf) {
          st[mf][nf] = mfma16(a0, qf[nf][0], st[mf][nf]);
          st[mf][nf] = mfma16(a1, qf[nf][1], st[mf][nf]);
        }
      }
      if (kv0 + 63 > qw) {  // diagonal tile: causal mask
#pragma unroll
        for (int mf = 0; mf < 4; ++mf)
#pragma unroll
          for (int nf = 0; nf < 2; ++nf)
#pragma unroll
            for (int r = 0; r < 4; ++r)
              if (kv0 + mf * 16 + g * 4 + r > qw + nf * 16 + q)
                st[mf][nf][r] = -INFINITY;
      }
#pragma unroll
      for (int nf = 0; nf < 2; ++nf) {
        float vmax = -INFINITY;
#pragma unroll
        for (int mf = 0; mf < 4; ++mf)
#pragma unroll
          for (int r = 0; r < 4; ++r) vmax = fmaxf(vmax, st[mf][nf][r]);
        vmax = fmaxf(vmax, __shfl_xor(vmax, 16));
        vmax = fmaxf(vmax, __shfl_xor(vmax, 32));
        const float mn = fmaxf(m_run[nf], vmax);
        const float corr = __expf(m_run[nf] - mn);
        m_run[nf] = mn;
        float ls = 0.f;
#pragma unroll
        for (int mf = 0; mf < 4; ++mf) {
          ushort4 pk;
#pragma unroll
          for (int r = 0; r < 4; ++r) {
            const float p = __expf(st[mf][nf][r] - mn);
            ls += p;
            ((unsigned short*)&pk)[r] = f2bf(p);
          }
          const int prow = w * 32 + nf * 16 + q;
          *(ushort4*)(Psm + ((prow * 128 + mf * 32 + g * 8) ^ ((prow & 7) << 4))) = pk;
        }
        ls += __shfl_xor(ls, 16);
        ls += __shfl_xor(ls, 32);
        l_run[nf] = l_run[nf] * corr + ls;
#pragma unroll
        for (int mfd = 0; mfd < 4; ++mfd) yt[mfd][nf] *= corr;
      }
      // PV: Y^T[d][q] += Vt * P^T (per-wave P slice; same-wave LDS dep)
#pragma unroll
      for (int kf = 0; kf < 2; ++kf) {
        bf16x8 pb[2];
#pragma unroll
        for (int nf = 0; nf < 2; ++nf) {
          const int prow = w * 32 + nf * 16 + q;
          pb[nf] = ld16(Psm + ((prow * 128 + kf * 64 + g * 16) ^ ((prow & 7) << 4)));
        }
#pragma unroll
        for (int mfd = 0; mfd < 4; ++mfd) {
          const int vrow = mfd * 16 + q;
          const bf16x8 vv = ld16(Vsm + ((vrow * 128 + kf * 64 + g * 16) ^ ((vrow & 7) << 4)));
#pragma unroll
          for (int nf = 0; nf < 2; ++nf)
            yt[mfd][nf] = mfma16(vv, pb[nf], yt[mfd][nf]);
        }
      }
    }
  }

  const int b = bh >> 4, h = bh & 15;
#pragma unroll
  for (int nf = 0; nf < 2; ++nf) {
    const float inv = 1.f / l_run[nf];
    const int qr = qw + nf * 16 + q;
    unsigned short* yp = Yb + (size_t)(b * 2048 + qr) * 1024 + h * 64;
#pragma unroll
    for (int mfd = 0; mfd < 4; ++mfd) {
      ushort4 o4;
      o4.x = f2bf(yt[mfd][nf][0] * inv);
      o4.y = f2bf(yt[mfd][nf][1] * inv);
      o4.z = f2bf(yt[mfd][nf][2] * inv);
      o4.w = f2bf(yt[mfd][nf][3] * inv);
      *(ushort4*)(yp + mfd * 16 + g * 4) = o4;
    }
  }
}

extern "C" void kernel_launch(void* const* d_in, const int* in_sizes, int n_in,
                              void* d_out, int out_size, void* d_ws, size_t ws_size,
                              hipStream_t stream) {
  const float* x      = (const float*)d_in[0];
  const float* w_qkv  = (const float*)d_in[1];
  const float* b_qkv  = (const float*)d_in[2];
  const float* w_proj = (const float*)d_in[3];
  const float* b_proj = (const float*)d_in[4];
  float* out = (float*)d_out;
  char* ws = (char*)d_ws;

  // workspace layout (bytes)
  unsigned short* xb  = (unsigned short*)(ws);                       // 16 MB x bf16 [8192][1024]
  unsigned short* wqb = (unsigned short*)(ws + (size_t)(16 << 20));  //  6 MB w_qkv bf16 [3072][1024]
  unsigned short* wpb = (unsigned short*)(ws + (size_t)(22 << 20));  //  2 MB w_proj bf16 [1024][1024]
  unsigned short* Qb  = (unsigned short*)(ws + (size_t)(24 << 20));  // 16 MB Q  [64 bh][2048 t][64 d] (pre-scaled 1/8)
  unsigned short* Kb  = (unsigned short*)(ws + (size_t)(40 << 20));  // 16 MB K  [64 bh][2048 t][64 d]
  unsigned short* Vtb = (unsigned short*)(ws + (size_t)(56 << 20));  // 16 MB V^T [64 bh][64 d][2048 t]
  unsigned short* Yb  = (unsigned short*)(ws + (size_t)(72 << 20));  // 16 MB attn out bf16 [8192][1024]

  cvt_bf16<<<8192, 256, 0, stream>>>(x, xb, 8192 * 1024 / 4);
  cvt_bf16<<<3072, 256, 0, stream>>>(w_qkv, wqb, 3072 * 1024 / 4);
  cvt_bf16<<<1024, 256, 0, stream>>>(w_proj, wpb, 1024 * 1024 / 4);

  gemm_bt<3072, 1><<<dim3(64, 24), 256, 0, stream>>>(xb, wqb, b_qkv, nullptr, Qb, Kb, Vtb);
  attn_fwd<<<dim3(16, 64), 256, 0, stream>>>(Qb, Kb, Vtb, Yb);
  gemm_bt<1024, 0><<<dim3(64, 8), 256, 0, stream>>>(Yb, wpb, b_proj, out, nullptr, nullptr, nullptr);
}

// Round 4
// 255.293 us; speedup vs baseline: 1.0196x; 1.0196x over previous
//
#include <hip/hip_runtime.h>

typedef __bf16 bf16x8 __attribute__((ext_vector_type(8)));
typedef float f32x4 __attribute__((ext_vector_type(4)));

#define DI __device__ __forceinline__

// Pinned counted waitcnt: memory clobber + sched_barrier so global_load_lds
// intrinsics cannot be reordered around it (rule #18).
#define WAIT_VMCNT(N)                                        \
  do {                                                       \
    __builtin_amdgcn_sched_barrier(0);                       \
    asm volatile("s_waitcnt vmcnt(" #N ")" ::: "memory");    \
    __builtin_amdgcn_sched_barrier(0);                       \
  } while (0)

DI unsigned short f2bf(float f) {
  unsigned int u = __float_as_uint(f);
  u += 0x7FFFu + ((u >> 16) & 1u);
  return (unsigned short)(u >> 16);
}

DI unsigned cvt_pk_bf16(float a, float b) {  // lo=bf16(a), hi=bf16(b)
  unsigned r;
  asm("v_cvt_pk_bf16_f32 %0, %1, %2" : "=v"(r) : "v"(a), "v"(b));
  return r;
}

DI float exp2_fast(float x) {  // raw v_exp_f32 (2^x); exp2(-inf)=0
  float r;
  asm("v_exp_f32 %0, %1" : "=v"(r) : "v"(x));
  return r;
}

DI void fence() { asm volatile("" ::: "memory"); }
DI void bar() { fence(); __builtin_amdgcn_s_barrier(); fence(); }

DI bf16x8 ld16(const void* p) {
  union { uint4 u; bf16x8 b; } c;
  c.u = *reinterpret_cast<const uint4*>(p);
  return c.b;
}

DI f32x4 mfma16(bf16x8 a, bf16x8 b, f32x4 c) {
  return __builtin_amdgcn_mfma_f32_16x16x32_bf16(a, b, c, 0, 0, 0);
}

DI void gload_lds16(const void* g, void* l) {
  __builtin_amdgcn_global_load_lds(
      (const __attribute__((address_space(1))) unsigned int*)g,
      (__attribute__((address_space(3))) unsigned int*)l, 16, 0, 0);
}

// ---------------- fused fp32 -> bf16 convert (x, w_qkv, w_proj) ----------------
__global__ void cvt_all(const float* __restrict__ x, const float* __restrict__ wq,
                        const float* __restrict__ wp,
                        unsigned short* __restrict__ xb, unsigned short* __restrict__ wqb,
                        unsigned short* __restrict__ wpb) {
  int i = blockIdx.x * blockDim.x + threadIdx.x;  // float4 index
  const float* s;
  unsigned short* d;
  int off;
  if (i < 2097152) { s = x; d = xb; off = i; }
  else if (i < 2097152 + 786432) { s = wq; d = wqb; off = i - 2097152; }
  else { s = wp; d = wpb; off = i - (2097152 + 786432); }
  float4 v = reinterpret_cast<const float4*>(s)[off];
  uint2 o;
  o.x = cvt_pk_bf16(v.x, v.y);
  o.y = cvt_pk_bf16(v.z, v.w);
  reinterpret_cast<uint2*>(d)[off] = o;
}

// ---------------- GEMM: C[M,N] = A[M,K] * W[N,K]^T + bias ----------------
// PROVEN round-1 structure: 128x128 tile, BK=64, 4 waves (2x2), single-buffered
// LDS (A 16K | B 16K), full drain + barrier per K-step. XOR bank-swizzle on the
// pre-swizzled global source + again on ds_read (involution).
// MODE 0: out = fp32 row-major [M][N] (+bias)
// MODE 1: qkv scatter -> Q (scaled log2e/8), K head-major; V transposed [bh][d][t]
template <int N, int MODE>
__global__ __launch_bounds__(256)
void gemm_bt(const unsigned short* __restrict__ A,
             const unsigned short* __restrict__ W,
             const float* __restrict__ bias,
             float* __restrict__ out,
             unsigned short* __restrict__ qo,
             unsigned short* __restrict__ ko,
             unsigned short* __restrict__ vo) {
  constexpr int K = 1024;
  __shared__ __align__(16) char smem[32768];  // A tile 16K | B tile 16K
  char* Asm = smem;
  char* Bsm = smem + 16384;
  const int tid = threadIdx.x;
  const int ln = tid & 63;
  const int w  = tid >> 6;
  const int wm = w >> 1, wn = w & 1;
  const int g = ln >> 4, q = ln & 15;
  const int m0 = blockIdx.x * 128;
  const int n0 = blockIdx.y * 128;

  f32x4 acc[4][4] = {};

  for (int kt = 0; kt < K / 64; ++kt) {
    if (kt) bar();  // previous compute's LDS reads done before overwrite
#pragma unroll
    for (int i = 0; i < 4; ++i) {
      const int chunk = i * 4 + w;                 // [0,16): full 16 KB tile
      const int o = chunk * 1024 + ln * 16;
      const int row = o >> 7;
      const int colb = (o & 127) ^ ((row & 7) << 4);
      gload_lds16((const char*)A + ((size_t)(m0 + row) * K + kt * 64) * 2 + colb,
                  Asm + chunk * 1024);
      gload_lds16((const char*)W + ((size_t)(n0 + row) * K + kt * 64) * 2 + colb,
                  Bsm + chunk * 1024);
    }
    WAIT_VMCNT(0);
    bar();
#pragma unroll
    for (int ks = 0; ks < 2; ++ks) {
      bf16x8 av[4], bv[4];
#pragma unroll
      for (int mf = 0; mf < 4; ++mf) {
        const int row = wm * 64 + mf * 16 + q;
        av[mf] = ld16(Asm + ((row * 128 + ks * 64 + g * 16) ^ ((row & 7) << 4)));
      }
#pragma unroll
      for (int nf = 0; nf < 4; ++nf) {
        const int row = wn * 64 + nf * 16 + q;
        bv[nf] = ld16(Bsm + ((row * 128 + ks * 64 + g * 16) ^ ((row & 7) << 4)));
      }
#pragma unroll
      for (int mf = 0; mf < 4; ++mf)
#pragma unroll
        for (int nf = 0; nf < 4; ++nf)
          acc[mf][nf] = mfma16(av[mf], bv[nf], acc[mf][nf]);
    }
  }

#pragma unroll
  for (int nf = 0; nf < 4; ++nf) {
    const int col = n0 + wn * 64 + nf * 16 + q;
    const float bv = bias[col];
#pragma unroll
    for (int mf = 0; mf < 4; ++mf) {
      const int rbase = m0 + wm * 64 + mf * 16 + g * 4;
#pragma unroll
      for (int r = 0; r < 4; ++r) {
        const int row = rbase + r;
        const float v = acc[mf][nf][r] + bv;
        if constexpr (MODE == 0) {
          out[(size_t)row * N + col] = v;
        } else {
          const int b = row >> 11, t = row & 2047;
          if (col < 1024) {
            const int h = col >> 6, d = col & 63;
            // fold softmax scale 1/8 AND log2(e) so attention can use raw v_exp_f32
            qo[((((size_t)b * 16 + h) << 11) + t) * 64 + d] = f2bf(v * 0.18033688011112042f);
          } else if (col < 2048) {
            const int c = col - 1024;
            const int h = c >> 6, d = c & 63;
            ko[((((size_t)b * 16 + h) << 11) + t) * 64 + d] = f2bf(v);
          } else {
            const int c = col - 2048;
            const int h = c >> 6, d = c & 63;
            vo[((((size_t)b * 16 + h) << 6) + d) * 2048 + t] = f2bf(v);
          }
        }
      }
    }
  }
}

// ---------------- flash attention (causal), swapped-operand, double-buffered ----------------
// grid: (16, 64) but qt = 15 - blockIdx.x (heavy blocks dispatch first).
// 4 waves, wave w owns q rows [q0+32w, q0+32w+32). KVBLK=64, K/V dbuf'd in LDS
// (K 8K + V 8K per buf -- verified in-bounds). S^T = mfma(K, Q) in base-2 domain
// (Q pre-scaled by log2e/8); softmax reduce via in-lane max chains + shfl_xor 16/32;
// exact-skip rescale; P via cvt_pk -> swizzled LDS.
__global__ __launch_bounds__(256)
void attn_fwd(const unsigned short* __restrict__ Qb,
              const unsigned short* __restrict__ Kb,
              const unsigned short* __restrict__ Vtb,
              unsigned short* __restrict__ Yb) {
  __shared__ __align__(16) char smem[49152];
  // buf0: K [0,8K) V [8K,16K); buf1: K [16K,24K) V [24K,32K); P [32K,48K)
  char* Psm = smem + 32768;
  const int tid = threadIdx.x;
  const int ln = tid & 63;
  const int w = tid >> 6;
  const int g = ln >> 4, q = ln & 15;
  const int qt = 15 - blockIdx.x;
  const int bh = blockIdx.y;
  const int q0 = qt * 128;
  const int qw = q0 + w * 32;
  const size_t base = (size_t)bh * 2048 * 64;  // elements

  bf16x8 qf[2][2];
#pragma unroll
  for (int nf = 0; nf < 2; ++nf)
#pragma unroll
    for (int kf = 0; kf < 2; ++kf)
      qf[nf][kf] = ld16(Qb + base + (size_t)(qw + nf * 16 + q) * 64 + kf * 32 + g * 8);
  WAIT_VMCNT(0);  // drain Q loads so the stage-pipeline vmcnt counts stay exact

  float m_run[2] = {-INFINITY, -INFINITY};
  float l_run[2] = {0.f, 0.f};
  f32x4 yt[4][2] = {};

  auto stage = [&](int j, int buf) {
    char* Kd = smem + buf * 16384;
    char* Vd = Kd + 8192;
    const int kv0 = j << 6;
    const char* Kg = (const char*)(Kb + base + (size_t)kv0 * 64);
    const char* Vg = (const char*)(Vtb + base) + kv0 * 2;
#pragma unroll
    for (int i = 0; i < 2; ++i) {
      const int chunk = i * 4 + w;                 // [0,8): 8 KB per tile
      const int o = chunk * 1024 + ln * 16;
      const int row = o >> 7;
      const int colb = (o & 127) ^ ((row & 7) << 4);
      gload_lds16(Kg + row * 128 + colb, Kd + chunk * 1024);
      gload_lds16(Vg + (size_t)row * 4096 + colb, Vd + chunk * 1024);
    }
  };

  const int nkv = (q0 >> 6) + 2;
  stage(0, 0);
  for (int j = 0; j < nkv; ++j) {
    if (j + 1 < nkv) {
      stage(j + 1, (j + 1) & 1);
      WAIT_VMCNT(4);
    } else {
      WAIT_VMCNT(0);
    }
    bar();

    const int kv0 = j << 6;
    const char* Ksm = smem + (j & 1) * 16384;
    const char* Vsm = Ksm + 8192;
    const bool active = (kv0 <= qw + 31);
    if (active) {
      f32x4 st[4][2] = {};
      __builtin_amdgcn_s_setprio(1);
#pragma unroll
      for (int mf = 0; mf < 4; ++mf) {
        const int row = mf * 16 + q;
        const int swz = (row & 7) << 4;
        const bf16x8 a0 = ld16(Ksm + ((row * 128 + g * 16) ^ swz));
        const bf16x8 a1 = ld16(Ksm + ((row * 128 + 64 + g * 16) ^ swz));
#pragma unroll
        for (int nf = 0; nf < 2; ++nf) {
          st[mf][nf] = mfma16(a0, qf[nf][0], st[mf][nf]);
          st[mf][nf] = mfma16(a1, qf[nf][1], st[mf][nf]);
        }
      }
      __builtin_amdgcn_s_setprio(0);
      if (kv0 + 63 > qw) {  // diagonal tile: causal mask
#pragma unroll
        for (int mf = 0; mf < 4; ++mf)
#pragma unroll
          for (int nf = 0; nf < 2; ++nf)
#pragma unroll
            for (int r = 0; r < 4; ++r)
              if (kv0 + mf * 16 + g * 4 + r > qw + nf * 16 + q)
                st[mf][nf][r] = -INFINITY;
      }
#pragma unroll
      for (int nf = 0; nf < 2; ++nf) {
        float vmax = -INFINITY;
#pragma unroll
        for (int mf = 0; mf < 4; ++mf) {
          const f32x4 v = st[mf][nf];
          vmax = fmaxf(fmaxf(vmax, fmaxf(v[0], v[1])), fmaxf(v[2], v[3]));
        }
        vmax = fmaxf(vmax, __shfl_xor(vmax, 16));
        vmax = fmaxf(vmax, __shfl_xor(vmax, 32));
        const float mo = m_run[nf];
        if (__any(vmax > mo)) {  // exact skip: if no lane grows, corr == 1 exactly
          const float mn = fmaxf(mo, vmax);
          const float corr = exp2_fast(mo - mn);
          m_run[nf] = mn;
          l_run[nf] *= corr;
#pragma unroll
          for (int mfd = 0; mfd < 4; ++mfd) yt[mfd][nf] *= corr;
        }
        const float mcur = m_run[nf];
        float ls = 0.f;
#pragma unroll
        for (int mf = 0; mf < 4; ++mf) {
          f32x4 p;
#pragma unroll
          for (int r = 0; r < 4; ++r) p[r] = exp2_fast(st[mf][nf][r] - mcur);
          ls += (p[0] + p[1]) + (p[2] + p[3]);
          uint2 pk2;
          pk2.x = cvt_pk_bf16(p[0], p[1]);
          pk2.y = cvt_pk_bf16(p[2], p[3]);
          const int prow = w * 32 + nf * 16 + q;
          *(uint2*)(Psm + ((prow * 128 + mf * 32 + g * 8) ^ ((prow & 7) << 4))) = pk2;
        }
        ls += __shfl_xor(ls, 16);
        ls += __shfl_xor(ls, 32);
        l_run[nf] += ls;
      }
      // PV: Y^T[d][q] += Vt * P^T (per-wave P slice; same-wave LDS dep, in-order DS pipe)
      __builtin_amdgcn_s_setprio(1);
#pragma unroll
      for (int kf = 0; kf < 2; ++kf) {
        bf16x8 pb[2];
#pragma unroll
        for (int nf = 0; nf < 2; ++nf) {
          const int prow = w * 32 + nf * 16 + q;
          pb[nf] = ld16(Psm + ((prow * 128 + kf * 64 + g * 16) ^ ((prow & 7) << 4)));
        }
#pragma unroll
        for (int mfd = 0; mfd < 4; ++mfd) {
          const int vrow = mfd * 16 + q;
          const bf16x8 vv = ld16(Vsm + ((vrow * 128 + kf * 64 + g * 16) ^ ((vrow & 7) << 4)));
#pragma unroll
          for (int nf = 0; nf < 2; ++nf)
            yt[mfd][nf] = mfma16(vv, pb[nf], yt[mfd][nf]);
        }
      }
      __builtin_amdgcn_s_setprio(0);
    }
    bar();
  }

  const int b = bh >> 4, h = bh & 15;
#pragma unroll
  for (int nf = 0; nf < 2; ++nf) {
    const float inv = 1.f / l_run[nf];
    const int qr = qw + nf * 16 + q;
    unsigned short* yp = Yb + (size_t)(b * 2048 + qr) * 1024 + h * 64;
#pragma unroll
    for (int mfd = 0; mfd < 4; ++mfd) {
      uint2 o2;
      o2.x = cvt_pk_bf16(yt[mfd][nf][0] * inv, yt[mfd][nf][1] * inv);
      o2.y = cvt_pk_bf16(yt[mfd][nf][2] * inv, yt[mfd][nf][3] * inv);
      *(uint2*)(yp + mfd * 16 + g * 4) = o2;
    }
  }
}

extern "C" void kernel_launch(void* const* d_in, const int* in_sizes, int n_in,
                              void* d_out, int out_size, void* d_ws, size_t ws_size,
                              hipStream_t stream) {
  const float* x      = (const float*)d_in[0];
  const float* w_qkv  = (const float*)d_in[1];
  const float* b_qkv  = (const float*)d_in[2];
  const float* w_proj = (const float*)d_in[3];
  const float* b_proj = (const float*)d_in[4];
  float* out = (float*)d_out;
  char* ws = (char*)d_ws;

  unsigned short* xb  = (unsigned short*)(ws);                       // 16 MB x bf16
  unsigned short* wqb = (unsigned short*)(ws + (size_t)(16 << 20));  //  6 MB w_qkv bf16
  unsigned short* wpb = (unsigned short*)(ws + (size_t)(22 << 20));  //  2 MB w_proj bf16
  unsigned short* Qb  = (unsigned short*)(ws + (size_t)(24 << 20));  // 16 MB Q (pre-scaled log2e/8)
  unsigned short* Kb  = (unsigned short*)(ws + (size_t)(40 << 20));  // 16 MB K [bh][t][d]
  unsigned short* Vtb = (unsigned short*)(ws + (size_t)(56 << 20));  // 16 MB V^T [bh][d][t]
  unsigned short* Yb  = (unsigned short*)(ws + (size_t)(72 << 20));  // 16 MB attn out bf16

  cvt_all<<<12288, 256, 0, stream>>>(x, w_qkv, w_proj, xb, wqb, wpb);
  gemm_bt<3072, 1><<<dim3(64, 24), 256, 0, stream>>>(xb, wqb, b_qkv, nullptr, Qb, Kb, Vtb);
  attn_fwd<<<dim3(16, 64), 256, 0, stream>>>(Qb, Kb, Vtb, Yb);
  gemm_bt<1024, 0><<<dim3(64, 8), 256, 0, stream>>>(Yb, wpb, b_proj, out, nullptr, nullptr, nullptr);
}

// Round 5
// 189.096 us; speedup vs baseline: 1.3765x; 1.3501x over previous
//
#include <hip/hip_runtime.h>

typedef __bf16 bf16x8 __attribute__((ext_vector_type(8)));
typedef float f32x4 __attribute__((ext_vector_type(4)));

#define DI __device__ __forceinline__

// Pinned counted waitcnt: memory clobber + sched_barrier so global_load_lds
// intrinsics cannot be reordered around it (rule #18).
#define WAIT_VMCNT(N)                                        \
  do {                                                       \
    __builtin_amdgcn_sched_barrier(0);                       \
    asm volatile("s_waitcnt vmcnt(" #N ")" ::: "memory");    \
    __builtin_amdgcn_sched_barrier(0);                       \
  } while (0)

DI unsigned short f2bf(float f) {
  unsigned int u = __float_as_uint(f);
  u += 0x7FFFu + ((u >> 16) & 1u);
  return (unsigned short)(u >> 16);
}

DI unsigned cvt_pk_bf16(float a, float b) {  // lo=bf16(a), hi=bf16(b)
  unsigned r;
  asm("v_cvt_pk_bf16_f32 %0, %1, %2" : "=v"(r) : "v"(a), "v"(b));
  return r;
}

DI float exp2_fast(float x) {  // raw v_exp_f32 (2^x); exp2(-inf)=0
  float r;
  asm("v_exp_f32 %0, %1" : "=v"(r) : "v"(x));
  return r;
}

DI void fence() { asm volatile("" ::: "memory"); }
DI void bar() { fence(); __builtin_amdgcn_s_barrier(); fence(); }

DI bf16x8 ld16(const void* p) {
  union { uint4 u; bf16x8 b; } c;
  c.u = *reinterpret_cast<const uint4*>(p);
  return c.b;
}

DI f32x4 mfma16(bf16x8 a, bf16x8 b, f32x4 c) {
  return __builtin_amdgcn_mfma_f32_16x16x32_bf16(a, b, c, 0, 0, 0);
}

DI void gload_lds16(const void* g, void* l) {
  __builtin_amdgcn_global_load_lds(
      (const __attribute__((address_space(1))) unsigned int*)g,
      (__attribute__((address_space(3))) unsigned int*)l, 16, 0, 0);
}

// ---------------- fused fp32 -> bf16 convert (x, w_qkv, w_proj) ----------------
__global__ void cvt_all(const float* __restrict__ x, const float* __restrict__ wq,
                        const float* __restrict__ wp,
                        unsigned short* __restrict__ xb, unsigned short* __restrict__ wqb,
                        unsigned short* __restrict__ wpb) {
  int i = blockIdx.x * blockDim.x + threadIdx.x;  // float4 index
  const float* s;
  unsigned short* d;
  int off;
  if (i < 2097152) { s = x; d = xb; off = i; }
  else if (i < 2097152 + 786432) { s = wq; d = wqb; off = i - 2097152; }
  else { s = wp; d = wpb; off = i - (2097152 + 786432); }
  float4 v = reinterpret_cast<const float4*>(s)[off];
  uint2 o;
  o.x = cvt_pk_bf16(v.x, v.y);
  o.y = cvt_pk_bf16(v.z, v.w);
  reinterpret_cast<uint2*>(d)[off] = o;
}

// ---------------- GEMM: C[M,N] = A[M,K] * W[N,K]^T + bias ----------------
// PROVEN round-1 structure: 128x128 tile, BK=64, 4 waves (2x2), single-buffered
// LDS (A 16K | B 16K), full drain + barrier per K-step. XOR bank-swizzle on the
// pre-swizzled global source + again on ds_read (involution).
// MODE 0: out = fp32 row-major [M][N] (+bias)
// MODE 1: qkv scatter -> Q (scaled log2e/8), K head-major; V transposed [bh][d][t]
template <int N, int MODE>
__global__ __launch_bounds__(256)
void gemm_bt(const unsigned short* __restrict__ A,
             const unsigned short* __restrict__ W,
             const float* __restrict__ bias,
             float* __restrict__ out,
             unsigned short* __restrict__ qo,
             unsigned short* __restrict__ ko,
             unsigned short* __restrict__ vo) {
  constexpr int K = 1024;
  __shared__ __align__(16) char smem[32768];  // A tile 16K | B tile 16K
  char* Asm = smem;
  char* Bsm = smem + 16384;
  const int tid = threadIdx.x;
  const int ln = tid & 63;
  const int w  = tid >> 6;
  const int wm = w >> 1, wn = w & 1;
  const int g = ln >> 4, q = ln & 15;
  const int m0 = blockIdx.x * 128;
  const int n0 = blockIdx.y * 128;

  f32x4 acc[4][4] = {};

  for (int kt = 0; kt < K / 64; ++kt) {
    if (kt) bar();  // previous compute's LDS reads done before overwrite
#pragma unroll
    for (int i = 0; i < 4; ++i) {
      const int chunk = i * 4 + w;                 // [0,16): full 16 KB tile
      const int o = chunk * 1024 + ln * 16;
      const int row = o >> 7;
      const int colb = (o & 127) ^ ((row & 7) << 4);
      gload_lds16((const char*)A + ((size_t)(m0 + row) * K + kt * 64) * 2 + colb,
                  Asm + chunk * 1024);
      gload_lds16((const char*)W + ((size_t)(n0 + row) * K + kt * 64) * 2 + colb,
                  Bsm + chunk * 1024);
    }
    WAIT_VMCNT(0);
    bar();
#pragma unroll
    for (int ks = 0; ks < 2; ++ks) {
      bf16x8 av[4], bv[4];
#pragma unroll
      for (int mf = 0; mf < 4; ++mf) {
        const int row = wm * 64 + mf * 16 + q;
        av[mf] = ld16(Asm + ((row * 128 + ks * 64 + g * 16) ^ ((row & 7) << 4)));
      }
#pragma unroll
      for (int nf = 0; nf < 4; ++nf) {
        const int row = wn * 64 + nf * 16 + q;
        bv[nf] = ld16(Bsm + ((row * 128 + ks * 64 + g * 16) ^ ((row & 7) << 4)));
      }
#pragma unroll
      for (int mf = 0; mf < 4; ++mf)
#pragma unroll
        for (int nf = 0; nf < 4; ++nf)
          acc[mf][nf] = mfma16(av[mf], bv[nf], acc[mf][nf]);
    }
  }

#pragma unroll
  for (int nf = 0; nf < 4; ++nf) {
    const int col = n0 + wn * 64 + nf * 16 + q;
    const float bv = bias[col];
#pragma unroll
    for (int mf = 0; mf < 4; ++mf) {
      const int rbase = m0 + wm * 64 + mf * 16 + g * 4;
#pragma unroll
      for (int r = 0; r < 4; ++r) {
        const int row = rbase + r;
        const float v = acc[mf][nf][r] + bv;
        if constexpr (MODE == 0) {
          out[(size_t)row * N + col] = v;
        } else {
          const int b = row >> 11, t = row & 2047;
          if (col < 1024) {
            const int h = col >> 6, d = col & 63;
            // fold softmax scale 1/8 AND log2(e) so attention can use raw v_exp_f32
            qo[((((size_t)b * 16 + h) << 11) + t) * 64 + d] = f2bf(v * 0.18033688011112042f);
          } else if (col < 2048) {
            const int c = col - 1024;
            const int h = c >> 6, d = c & 63;
            ko[((((size_t)b * 16 + h) << 11) + t) * 64 + d] = f2bf(v);
          } else {
            const int c = col - 2048;
            const int h = c >> 6, d = c & 63;
            vo[((((size_t)b * 16 + h) << 6) + d) * 2048 + t] = f2bf(v);
          }
        }
      }
    }
  }
}

// ---------------- flash attention (causal), swapped-operand, double-buffered ----------------
// grid: (bh=64, 16) with qt = 15 - blockIdx.y  =>  linear dispatch order emits ALL
// 64 heaviest (32-iteration diagonal) blocks first, then qt=14, ... (LPT schedule).
// Same-bh blocks are 64 apart in linear id (64 % 8 XCDs == 0) -> all q-tiles of a
// head land on one XCD; shared K/V panel (512 KB) becomes XCD-L2-resident.
// 4 waves, wave w owns q rows [q0+32w, q0+32w+32). KVBLK=64, K/V dbuf'd in LDS.
// S^T = mfma(K, Q) in base-2 domain (Q pre-scaled by log2e/8); softmax reduce via
// in-lane max chains + shfl_xor 16/32; exact-skip rescale; P via cvt_pk -> swizzled LDS.
__global__ __launch_bounds__(256)
void attn_fwd(const unsigned short* __restrict__ Qb,
              const unsigned short* __restrict__ Kb,
              const unsigned short* __restrict__ Vtb,
              unsigned short* __restrict__ Yb) {
  __shared__ __align__(16) char smem[49152];
  // buf0: K [0,8K) V [8K,16K); buf1: K [16K,24K) V [24K,32K); P [32K,48K)
  char* Psm = smem + 32768;
  const int tid = threadIdx.x;
  const int ln = tid & 63;
  const int w = tid >> 6;
  const int g = ln >> 4, q = ln & 15;
  const int qt = 15 - blockIdx.y;   // heavy-first across the WHOLE grid
  const int bh = blockIdx.x;
  const int q0 = qt * 128;
  const int qw = q0 + w * 32;
  const size_t base = (size_t)bh * 2048 * 64;  // elements

  bf16x8 qf[2][2];
#pragma unroll
  for (int nf = 0; nf < 2; ++nf)
#pragma unroll
    for (int kf = 0; kf < 2; ++kf)
      qf[nf][kf] = ld16(Qb + base + (size_t)(qw + nf * 16 + q) * 64 + kf * 32 + g * 8);
  WAIT_VMCNT(0);  // drain Q loads so the stage-pipeline vmcnt counts stay exact

  float m_run[2] = {-INFINITY, -INFINITY};
  float l_run[2] = {0.f, 0.f};
  f32x4 yt[4][2] = {};

  auto stage = [&](int j, int buf) {
    char* Kd = smem + buf * 16384;
    char* Vd = Kd + 8192;
    const int kv0 = j << 6;
    const char* Kg = (const char*)(Kb + base + (size_t)kv0 * 64);
    const char* Vg = (const char*)(Vtb + base) + kv0 * 2;
#pragma unroll
    for (int i = 0; i < 2; ++i) {
      const int chunk = i * 4 + w;                 // [0,8): 8 KB per tile
      const int o = chunk * 1024 + ln * 16;
      const int row = o >> 7;
      const int colb = (o & 127) ^ ((row & 7) << 4);
      gload_lds16(Kg + row * 128 + colb, Kd + chunk * 1024);
      gload_lds16(Vg + (size_t)row * 4096 + colb, Vd + chunk * 1024);
    }
  };

  const int nkv = (q0 >> 6) + 2;
  stage(0, 0);
  for (int j = 0; j < nkv; ++j) {
    if (j + 1 < nkv) {
      stage(j + 1, (j + 1) & 1);
      WAIT_VMCNT(4);
    } else {
      WAIT_VMCNT(0);
    }
    bar();

    const int kv0 = j << 6;
    const char* Ksm = smem + (j & 1) * 16384;
    const char* Vsm = Ksm + 8192;
    const bool active = (kv0 <= qw + 31);
    if (active) {
      f32x4 st[4][2] = {};
      __builtin_amdgcn_s_setprio(1);
#pragma unroll
      for (int mf = 0; mf < 4; ++mf) {
        const int row = mf * 16 + q;
        const int swz = (row & 7) << 4;
        const bf16x8 a0 = ld16(Ksm + ((row * 128 + g * 16) ^ swz));
        const bf16x8 a1 = ld16(Ksm + ((row * 128 + 64 + g * 16) ^ swz));
#pragma unroll
        for (int nf = 0; nf < 2; ++nf) {
          st[mf][nf] = mfma16(a0, qf[nf][0], st[mf][nf]);
          st[mf][nf] = mfma16(a1, qf[nf][1], st[mf][nf]);
        }
      }
      __builtin_amdgcn_s_setprio(0);
      if (kv0 + 63 > qw) {  // diagonal tile: causal mask
#pragma unroll
        for (int mf = 0; mf < 4; ++mf)
#pragma unroll
          for (int nf = 0; nf < 2; ++nf)
#pragma unroll
            for (int r = 0; r < 4; ++r)
              if (kv0 + mf * 16 + g * 4 + r > qw + nf * 16 + q)
                st[mf][nf][r] = -INFINITY;
      }
#pragma unroll
      for (int nf = 0; nf < 2; ++nf) {
        float vmax = -INFINITY;
#pragma unroll
        for (int mf = 0; mf < 4; ++mf) {
          const f32x4 v = st[mf][nf];
          vmax = fmaxf(fmaxf(vmax, fmaxf(v[0], v[1])), fmaxf(v[2], v[3]));
        }
        vmax = fmaxf(vmax, __shfl_xor(vmax, 16));
        vmax = fmaxf(vmax, __shfl_xor(vmax, 32));
        const float mo = m_run[nf];
        if (__any(vmax > mo)) {  // exact skip: if no lane grows, corr == 1 exactly
          const float mn = fmaxf(mo, vmax);
          const float corr = exp2_fast(mo - mn);
          m_run[nf] = mn;
          l_run[nf] *= corr;
#pragma unroll
          for (int mfd = 0; mfd < 4; ++mfd) yt[mfd][nf] *= corr;
        }
        const float mcur = m_run[nf];
        float ls = 0.f;
#pragma unroll
        for (int mf = 0; mf < 4; ++mf) {
          f32x4 p;
#pragma unroll
          for (int r = 0; r < 4; ++r) p[r] = exp2_fast(st[mf][nf][r] - mcur);
          ls += (p[0] + p[1]) + (p[2] + p[3]);
          uint2 pk2;
          pk2.x = cvt_pk_bf16(p[0], p[1]);
          pk2.y = cvt_pk_bf16(p[2], p[3]);
          const int prow = w * 32 + nf * 16 + q;
          *(uint2*)(Psm + ((prow * 128 + mf * 32 + g * 8) ^ ((prow & 7) << 4))) = pk2;
        }
        ls += __shfl_xor(ls, 16);
        ls += __shfl_xor(ls, 32);
        l_run[nf] += ls;
      }
      // PV: Y^T[d][q] += Vt * P^T (per-wave P slice; same-wave LDS dep, in-order DS pipe)
      __builtin_amdgcn_s_setprio(1);
#pragma unroll
      for (int kf = 0; kf < 2; ++kf) {
        bf16x8 pb[2];
#pragma unroll
        for (int nf = 0; nf < 2; ++nf) {
          const int prow = w * 32 + nf * 16 + q;
          pb[nf] = ld16(Psm + ((prow * 128 + kf * 64 + g * 16) ^ ((prow & 7) << 4)));
        }
#pragma unroll
        for (int mfd = 0; mfd < 4; ++mfd) {
          const int vrow = mfd * 16 + q;
          const bf16x8 vv = ld16(Vsm + ((vrow * 128 + kf * 64 + g * 16) ^ ((vrow & 7) << 4)));
#pragma unroll
          for (int nf = 0; nf < 2; ++nf)
            yt[mfd][nf] = mfma16(vv, pb[nf], yt[mfd][nf]);
        }
      }
      __builtin_amdgcn_s_setprio(0);
    }
    bar();
  }

  const int b = bh >> 4, h = bh & 15;
#pragma unroll
  for (int nf = 0; nf < 2; ++nf) {
    const float inv = 1.f / l_run[nf];
    const int qr = qw + nf * 16 + q;
    unsigned short* yp = Yb + (size_t)(b * 2048 + qr) * 1024 + h * 64;
#pragma unroll
    for (int mfd = 0; mfd < 4; ++mfd) {
      uint2 o2;
      o2.x = cvt_pk_bf16(yt[mfd][nf][0] * inv, yt[mfd][nf][1] * inv);
      o2.y = cvt_pk_bf16(yt[mfd][nf][2] * inv, yt[mfd][nf][3] * inv);
      *(uint2*)(yp + mfd * 16 + g * 4) = o2;
    }
  }
}

extern "C" void kernel_launch(void* const* d_in, const int* in_sizes, int n_in,
                              void* d_out, int out_size, void* d_ws, size_t ws_size,
                              hipStream_t stream) {
  const float* x      = (const float*)d_in[0];
  const float* w_qkv  = (const float*)d_in[1];
  const float* b_qkv  = (const float*)d_in[2];
  const float* w_proj = (const float*)d_in[3];
  const float* b_proj = (const float*)d_in[4];
  float* out = (float*)d_out;
  char* ws = (char*)d_ws;

  unsigned short* xb  = (unsigned short*)(ws);                       // 16 MB x bf16
  unsigned short* wqb = (unsigned short*)(ws + (size_t)(16 << 20));  //  6 MB w_qkv bf16
  unsigned short* wpb = (unsigned short*)(ws + (size_t)(22 << 20));  //  2 MB w_proj bf16
  unsigned short* Qb  = (unsigned short*)(ws + (size_t)(24 << 20));  // 16 MB Q (pre-scaled log2e/8)
  unsigned short* Kb  = (unsigned short*)(ws + (size_t)(40 << 20));  // 16 MB K [bh][t][d]
  unsigned short* Vtb = (unsigned short*)(ws + (size_t)(56 << 20));  // 16 MB V^T [bh][d][t]
  unsigned short* Yb  = (unsigned short*)(ws + (size_t)(72 << 20));  // 16 MB attn out bf16

  cvt_all<<<12288, 256, 0, stream>>>(x, w_qkv, w_proj, xb, wqb, wpb);
  gemm_bt<3072, 1><<<dim3(64, 24), 256, 0, stream>>>(xb, wqb, b_qkv, nullptr, Qb, Kb, Vtb);
  attn_fwd<<<dim3(64, 16), 256, 0, stream>>>(Qb, Kb, Vtb, Yb);
  gemm_bt<1024, 0><<<dim3(64, 8), 256, 0, stream>>>(Yb, wpb, b_proj, out, nullptr, nullptr, nullptr);
}

// Round 7
// 174.173 us; speedup vs baseline: 1.4944x; 1.0857x over previous
//
#include <hip/hip_runtime.h>

typedef __bf16 bf16x8 __attribute__((ext_vector_type(8)));
typedef float f32x4 __attribute__((ext_vector_type(4)));

#define DI __device__ __forceinline__

// Pinned counted waitcnt: memory clobber + sched_barrier so global_load_lds
// intrinsics cannot be reordered around it (rule #18).
#define WAIT_VMCNT(N)                                        \
  do {                                                       \
    __builtin_amdgcn_sched_barrier(0);                       \
    asm volatile("s_waitcnt vmcnt(" #N ")" ::: "memory");    \
    __builtin_amdgcn_sched_barrier(0);                       \
  } while (0)

DI unsigned short f2bf(float f) {
  unsigned int u = __float_as_uint(f);
  u += 0x7FFFu + ((u >> 16) & 1u);
  return (unsigned short)(u >> 16);
}

DI unsigned cvt_pk_bf16(float a, float b) {  // lo=bf16(a), hi=bf16(b)
  unsigned r;
  asm("v_cvt_pk_bf16_f32 %0, %1, %2" : "=v"(r) : "v"(a), "v"(b));
  return r;
}

DI float exp2_fast(float x) {  // raw v_exp_f32 (2^x); exp2(-inf)=0
  float r;
  asm("v_exp_f32 %0, %1" : "=v"(r) : "v"(x));
  return r;
}

DI void fence() { asm volatile("" ::: "memory"); }
DI void bar() { fence(); __builtin_amdgcn_s_barrier(); fence(); }

DI bf16x8 ld16(const void* p) {
  union { uint4 u; bf16x8 b; } c;
  c.u = *reinterpret_cast<const uint4*>(p);
  return c.b;
}

DI f32x4 mfma16(bf16x8 a, bf16x8 b, f32x4 c) {
  return __builtin_amdgcn_mfma_f32_16x16x32_bf16(a, b, c, 0, 0, 0);
}

DI void gload_lds16(const void* g, void* l) {
  __builtin_amdgcn_global_load_lds(
      (const __attribute__((address_space(1))) unsigned int*)g,
      (__attribute__((address_space(3))) unsigned int*)l, 16, 0, 0);
}

// ---------------- fused fp32 -> bf16 convert (x, w_qkv, w_proj) ----------------
__global__ void cvt_all(const float* __restrict__ x, const float* __restrict__ wq,
                        const float* __restrict__ wp,
                        unsigned short* __restrict__ xb, unsigned short* __restrict__ wqb,
                        unsigned short* __restrict__ wpb) {
  int i = blockIdx.x * blockDim.x + threadIdx.x;  // float4 index
  const float* s;
  unsigned short* d;
  int off;
  if (i < 2097152) { s = x; d = xb; off = i; }
  else if (i < 2097152 + 786432) { s = wq; d = wqb; off = i - 2097152; }
  else { s = wp; d = wpb; off = i - (2097152 + 786432); }
  float4 v = reinterpret_cast<const float4*>(s)[off];
  uint2 o;
  o.x = cvt_pk_bf16(v.x, v.y);
  o.y = cvt_pk_bf16(v.z, v.w);
  reinterpret_cast<uint2*>(d)[off] = o;
}

// ---------------- GEMM: C[M,N] = A[M,K] * W[N,K]^T + bias ----------------
// PROVEN round-1 structure: 128x128 tile, BK=64, 4 waves (2x2), single-buffered
// LDS (A 16K | B 16K), full drain + barrier per K-step. XOR bank-swizzle on the
// pre-swizzled global source + again on ds_read (involution).
// MODE 0: out = fp32 row-major [M][N] (+bias)
// MODE 1: qkv scatter -> Q (scaled log2e/8), K head-major; V transposed [bh][d][t]
//         (V^T stores packed as uint2: in-lane r's are 4 consecutive t)
template <int N, int MODE>
__global__ __launch_bounds__(256)
void gemm_bt(const unsigned short* __restrict__ A,
             const unsigned short* __restrict__ W,
             const float* __restrict__ bias,
             float* __restrict__ out,
             unsigned short* __restrict__ qo,
             unsigned short* __restrict__ ko,
             unsigned short* __restrict__ vo) {
  constexpr int K = 1024;
  __shared__ __align__(16) char smem[32768];  // A tile 16K | B tile 16K
  char* Asm = smem;
  char* Bsm = smem + 16384;
  const int tid = threadIdx.x;
  const int ln = tid & 63;
  const int w  = tid >> 6;
  const int wm = w >> 1, wn = w & 1;
  const int g = ln >> 4, q = ln & 15;
  const int m0 = blockIdx.x * 128;
  const int n0 = blockIdx.y * 128;

  f32x4 acc[4][4] = {};

  for (int kt = 0; kt < K / 64; ++kt) {
    if (kt) bar();  // previous compute's LDS reads done before overwrite
#pragma unroll
    for (int i = 0; i < 4; ++i) {
      const int chunk = i * 4 + w;                 // [0,16): full 16 KB tile
      const int o = chunk * 1024 + ln * 16;
      const int row = o >> 7;
      const int colb = (o & 127) ^ ((row & 7) << 4);
      gload_lds16((const char*)A + ((size_t)(m0 + row) * K + kt * 64) * 2 + colb,
                  Asm + chunk * 1024);
      gload_lds16((const char*)W + ((size_t)(n0 + row) * K + kt * 64) * 2 + colb,
                  Bsm + chunk * 1024);
    }
    WAIT_VMCNT(0);
    bar();
#pragma unroll
    for (int ks = 0; ks < 2; ++ks) {
      bf16x8 av[4], bv[4];
#pragma unroll
      for (int mf = 0; mf < 4; ++mf) {
        const int row = wm * 64 + mf * 16 + q;
        av[mf] = ld16(Asm + ((row * 128 + ks * 64 + g * 16) ^ ((row & 7) << 4)));
      }
#pragma unroll
      for (int nf = 0; nf < 4; ++nf) {
        const int row = wn * 64 + nf * 16 + q;
        bv[nf] = ld16(Bsm + ((row * 128 + ks * 64 + g * 16) ^ ((row & 7) << 4)));
      }
#pragma unroll
      for (int mf = 0; mf < 4; ++mf)
#pragma unroll
        for (int nf = 0; nf < 4; ++nf)
          acc[mf][nf] = mfma16(av[mf], bv[nf], acc[mf][nf]);
    }
  }

#pragma unroll
  for (int nf = 0; nf < 4; ++nf) {
    const int col = n0 + wn * 64 + nf * 16 + q;
    const float bv = bias[col];
#pragma unroll
    for (int mf = 0; mf < 4; ++mf) {
      const int rbase = m0 + wm * 64 + mf * 16 + g * 4;
      if constexpr (MODE == 0) {
#pragma unroll
        for (int r = 0; r < 4; ++r)
          out[(size_t)(rbase + r) * N + col] = acc[mf][nf][r] + bv;
      } else {
        const int b = rbase >> 11, t0 = rbase & 2047;  // 4 consecutive t, same b
        if (col < 1024) {
          const int h = col >> 6, d = col & 63;
          unsigned short* qp = qo + ((((size_t)b * 16 + h) << 11) + t0) * 64 + d;
#pragma unroll
          for (int r = 0; r < 4; ++r)
            qp[r * 64] = f2bf((acc[mf][nf][r] + bv) * 0.18033688011112042f);
        } else if (col < 2048) {
          const int c = col - 1024;
          const int h = c >> 6, d = c & 63;
          unsigned short* kp = ko + ((((size_t)b * 16 + h) << 11) + t0) * 64 + d;
#pragma unroll
          for (int r = 0; r < 4; ++r)
            kp[r * 64] = f2bf(acc[mf][nf][r] + bv);
        } else {
          const int c = col - 2048;
          const int h = c >> 6, d = c & 63;
          uint2 pk;
          pk.x = cvt_pk_bf16(acc[mf][nf][0] + bv, acc[mf][nf][1] + bv);
          pk.y = cvt_pk_bf16(acc[mf][nf][2] + bv, acc[mf][nf][3] + bv);
          *(uint2*)(vo + ((((size_t)b * 16 + h) << 6) + d) * 2048 + t0) = pk;
        }
      }
    }
  }
}

// ---------------- flash attention (causal), swapped-operand, double-buffered ----------------
// LOAD-BALANCED: grid (bh=64, pair=8); each block runs q-tiles {15-p, p} sequentially.
// Per-block iterations = (2(15-p)+2) + (2p+2) = 34, constant -> 512 identical blocks,
// single dispatch round, no drain. Same-bh blocks 64 apart (64%8==0) -> one XCD per
// head, K/V panel L2-resident.
// 4 waves, wave w owns q rows [q0+32w, q0+32w+32). KVBLK=64, K/V dbuf'd in LDS.
// S^T = mfma(K, Q) in base-2 domain (Q pre-scaled by log2e/8); softmax reduce via
// in-lane max chains + shfl_xor 16/32; exact-skip rescale; P via cvt_pk -> swizzled LDS.
__global__ __launch_bounds__(256)
void attn_fwd(const unsigned short* __restrict__ Qb,
              const unsigned short* __restrict__ Kb,
              const unsigned short* __restrict__ Vtb,
              unsigned short* __restrict__ Yb) {
  __shared__ __align__(16) char smem[49152];
  // buf0: K [0,8K) V [8K,16K); buf1: K [16K,24K) V [24K,32K); P [32K,48K)
  char* Psm = smem + 32768;
  const int tid = threadIdx.x;
  const int ln = tid & 63;
  const int w = tid >> 6;
  const int g = ln >> 4, q = ln & 15;
  const int bh = blockIdx.x;
  const int pair = blockIdx.y;
  const size_t base = (size_t)bh * 2048 * 64;  // elements
  const int b = bh >> 4, h = bh & 15;

  auto stage = [&](int j, int buf) {
    char* Kd = smem + buf * 16384;
    char* Vd = Kd + 8192;
    const int kv0 = j << 6;
    const char* Kg = (const char*)(Kb + base + (size_t)kv0 * 64);
    const char* Vg = (const char*)(Vtb + base) + kv0 * 2;
#pragma unroll
    for (int i = 0; i < 2; ++i) {
      const int chunk = i * 4 + w;                 // [0,8): 8 KB per tile
      const int o = chunk * 1024 + ln * 16;
      const int row = o >> 7;
      const int colb = (o & 127) ^ ((row & 7) << 4);
      gload_lds16(Kg + row * 128 + colb, Kd + chunk * 1024);
      gload_lds16(Vg + (size_t)row * 4096 + colb, Vd + chunk * 1024);
    }
  };

  auto run_qtile = [&](int qt) {
    const int q0 = qt * 128;
    const int qw = q0 + w * 32;

    bf16x8 qf[2][2];
#pragma unroll
    for (int nf = 0; nf < 2; ++nf)
#pragma unroll
      for (int kf = 0; kf < 2; ++kf)
        qf[nf][kf] = ld16(Qb + base + (size_t)(qw + nf * 16 + q) * 64 + kf * 32 + g * 8);
    WAIT_VMCNT(0);  // drains Q loads AND any prior epilogue stores: counts stay exact

    float m_run[2] = {-INFINITY, -INFINITY};
    float l_run[2] = {0.f, 0.f};
    f32x4 yt[4][2] = {};

    const int nkv = (q0 >> 6) + 2;
    stage(0, 0);
    for (int j = 0; j < nkv; ++j) {
      if (j + 1 < nkv) {
        stage(j + 1, (j + 1) & 1);
        WAIT_VMCNT(4);
      } else {
        WAIT_VMCNT(0);
      }
      bar();

      const int kv0 = j << 6;
      const char* Ksm = smem + (j & 1) * 16384;
      const char* Vsm = Ksm + 8192;
      const bool active = (kv0 <= qw + 31);
      if (active) {
        f32x4 st[4][2] = {};
        __builtin_amdgcn_s_setprio(1);
#pragma unroll
        for (int mf = 0; mf < 4; ++mf) {
          const int row = mf * 16 + q;
          const int swz = (row & 7) << 4;
          const bf16x8 a0 = ld16(Ksm + ((row * 128 + g * 16) ^ swz));
          const bf16x8 a1 = ld16(Ksm + ((row * 128 + 64 + g * 16) ^ swz));
#pragma unroll
          for (int nf = 0; nf < 2; ++nf) {
            st[mf][nf] = mfma16(a0, qf[nf][0], st[mf][nf]);
            st[mf][nf] = mfma16(a1, qf[nf][1], st[mf][nf]);
          }
        }
        __builtin_amdgcn_s_setprio(0);
        if (kv0 + 63 > qw) {  // diagonal tile: causal mask
#pragma unroll
          for (int mf = 0; mf < 4; ++mf)
#pragma unroll
            for (int nf = 0; nf < 2; ++nf)
#pragma unroll
              for (int r = 0; r < 4; ++r)
                if (kv0 + mf * 16 + g * 4 + r > qw + nf * 16 + q)
                  st[mf][nf][r] = -INFINITY;
        }
#pragma unroll
        for (int nf = 0; nf < 2; ++nf) {
          float vmax = -INFINITY;
#pragma unroll
          for (int mf = 0; mf < 4; ++mf) {
            const f32x4 v = st[mf][nf];
            vmax = fmaxf(fmaxf(vmax, fmaxf(v[0], v[1])), fmaxf(v[2], v[3]));
          }
          vmax = fmaxf(vmax, __shfl_xor(vmax, 16));
          vmax = fmaxf(vmax, __shfl_xor(vmax, 32));
          const float mo = m_run[nf];
          if (__any(vmax > mo)) {  // exact skip: if no lane grows, corr == 1 exactly
            const float mn = fmaxf(mo, vmax);
            const float corr = exp2_fast(mo - mn);
            m_run[nf] = mn;
            l_run[nf] *= corr;
#pragma unroll
            for (int mfd = 0; mfd < 4; ++mfd) yt[mfd][nf] *= corr;
          }
          const float mcur = m_run[nf];
          float ls = 0.f;
#pragma unroll
          for (int mf = 0; mf < 4; ++mf) {
            f32x4 p;
#pragma unroll
            for (int r = 0; r < 4; ++r) p[r] = exp2_fast(st[mf][nf][r] - mcur);
            ls += (p[0] + p[1]) + (p[2] + p[3]);
            uint2 pk2;
            pk2.x = cvt_pk_bf16(p[0], p[1]);
            pk2.y = cvt_pk_bf16(p[2], p[3]);
            const int prow = w * 32 + nf * 16 + q;
            *(uint2*)(Psm + ((prow * 128 + mf * 32 + g * 8) ^ ((prow & 7) << 4))) = pk2;
          }
          ls += __shfl_xor(ls, 16);
          ls += __shfl_xor(ls, 32);
          l_run[nf] += ls;
        }
        // PV: Y^T[d][q] += Vt * P^T (per-wave P slice; same-wave LDS dep, in-order DS pipe)
        __builtin_amdgcn_s_setprio(1);
#pragma unroll
        for (int kf = 0; kf < 2; ++kf) {
          bf16x8 pb[2];
#pragma unroll
          for (int nf = 0; nf < 2; ++nf) {
            const int prow = w * 32 + nf * 16 + q;
            pb[nf] = ld16(Psm + ((prow * 128 + kf * 64 + g * 16) ^ ((prow & 7) << 4)));
          }
#pragma unroll
          for (int mfd = 0; mfd < 4; ++mfd) {
            const int vrow = mfd * 16 + q;
            const bf16x8 vv = ld16(Vsm + ((vrow * 128 + kf * 64 + g * 16) ^ ((vrow & 7) << 4)));
#pragma unroll
            for (int nf = 0; nf < 2; ++nf)
              yt[mfd][nf] = mfma16(vv, pb[nf], yt[mfd][nf]);
          }
        }
        __builtin_amdgcn_s_setprio(0);
      }
      bar();
    }

#pragma unroll
    for (int nf = 0; nf < 2; ++nf) {
      const float inv = 1.f / l_run[nf];
      const int qr = qw + nf * 16 + q;
      unsigned short* yp = Yb + (size_t)(b * 2048 + qr) * 1024 + h * 64;
#pragma unroll
      for (int mfd = 0; mfd < 4; ++mfd) {
        uint2 o2;
        o2.x = cvt_pk_bf16(yt[mfd][nf][0] * inv, yt[mfd][nf][1] * inv);
        o2.y = cvt_pk_bf16(yt[mfd][nf][2] * inv, yt[mfd][nf][3] * inv);
        *(uint2*)(yp + mfd * 16 + g * 4) = o2;
      }
    }
  };

  run_qtile(15 - pair);  // heavy q-tile first
  run_qtile(pair);       // paired light q-tile: total iters = 34 for every block
}

extern "C" void kernel_launch(void* const* d_in, const int* in_sizes, int n_in,
                              void* d_out, int out_size, void* d_ws, size_t ws_size,
                              hipStream_t stream) {
  const float* x      = (const float*)d_in[0];
  const float* w_qkv  = (const float*)d_in[1];
  const float* b_qkv  = (const float*)d_in[2];
  const float* w_proj = (const float*)d_in[3];
  const float* b_proj = (const float*)d_in[4];
  float* out = (float*)d_out;
  char* ws = (char*)d_ws;

  unsigned short* xb  = (unsigned short*)(ws);                       // 16 MB x bf16
  unsigned short* wqb = (unsigned short*)(ws + (size_t)(16 << 20));  //  6 MB w_qkv bf16
  unsigned short* wpb = (unsigned short*)(ws + (size_t)(22 << 20));  //  2 MB w_proj bf16
  unsigned short* Qb  = (unsigned short*)(ws + (size_t)(24 << 20));  // 16 MB Q (pre-scaled log2e/8)
  unsigned short* Kb  = (unsigned short*)(ws + (size_t)(40 << 20));  // 16 MB K [bh][t][d]
  unsigned short* Vtb = (unsigned short*)(ws + (size_t)(56 << 20));  // 16 MB V^T [bh][d][t]
  unsigned short* Yb  = (unsigned short*)(ws + (size_t)(72 << 20));  // 16 MB attn out bf16

  cvt_all<<<12288, 256, 0, stream>>>(x, w_qkv, w_proj, xb, wqb, wpb);
  gemm_bt<3072, 1><<<dim3(64, 24), 256, 0, stream>>>(xb, wqb, b_qkv, nullptr, Qb, Kb, Vtb);
  attn_fwd<<<dim3(64, 8), 256, 0, stream>>>(Qb, Kb, Vtb, Yb);
  gemm_bt<1024, 0><<<dim3(64, 8), 256, 0, stream>>>(Yb, wpb, b_proj, out, nullptr, nullptr, nullptr);
}